// Round 9
// baseline (340.714 us; speedup 1.0000x reference)
//
#include <hip/hip_runtime.h>
#include <hip/hip_bf16.h>

typedef unsigned short u16;
typedef short short8_t __attribute__((ext_vector_type(8)));
typedef float f32x4 __attribute__((ext_vector_type(4)));

#define GLOBAL_AS(p) ((const __attribute__((address_space(1))) void*)(p))
#define LDS_AS(p)    ((__attribute__((address_space(3))) void*)(p))

__device__ __forceinline__ u16 f2bf(float f) {
    union { float f; unsigned int u; } x;
    x.f = f;
    unsigned int r = x.u + 0x7fffu + ((x.u >> 16) & 1u);   // RNE
    return (u16)(r >> 16);
}

// meta layout (ints), fits in 64 KiB:
//  [0] n_mtiles   [1] total_padded_rows
//  [2..42)   tile_expert
//  [42..82)  tile_base_row
//  [96..96+4096)   pair_row[t*2+j]  (row index of token t's j-th expert)
//  [4192..9312)    row_tok[row]     (token id, -1 = pad)
//  [9312..14432)   row_w[row]       (float weight)
#define M_NMT   0
#define M_TE    2
#define M_TB    42
#define M_PAIR  96
#define M_RTOK  4192
#define M_RW    9312

// ---------------------------------------------------------------------------
// Kernel 1: gate = h @ WG, top-2 sigmoid weights -> w[2048][8] fp32
// ---------------------------------------------------------------------------
__global__ __launch_bounds__(64) void gate_topk_kernel(
    const float* __restrict__ h, const float* __restrict__ wg, float* __restrict__ w) {
    const int t = blockIdx.x;
    const int lane = threadIdx.x;
    float acc[8];
#pragma unroll
    for (int g = 0; g < 8; ++g) acc[g] = 0.f;
    for (int e = lane; e < 1024; e += 64) {
        float hv = h[(size_t)t * 1024 + e];
        float4 r0 = *(const float4*)&wg[e * 8];
        float4 r1 = *(const float4*)&wg[e * 8 + 4];
        acc[0] += hv * r0.x; acc[1] += hv * r0.y; acc[2] += hv * r0.z; acc[3] += hv * r0.w;
        acc[4] += hv * r1.x; acc[5] += hv * r1.y; acc[6] += hv * r1.z; acc[7] += hv * r1.w;
    }
#pragma unroll
    for (int off = 32; off > 0; off >>= 1) {
#pragma unroll
        for (int g = 0; g < 8; ++g) acc[g] += __shfl_down(acc[g], off);
    }
    if (lane == 0) {
        int i1 = 0;
        for (int g = 1; g < 8; ++g) if (acc[g] > acc[i1]) i1 = g;   // lowest idx on ties
        int i2 = -1;
        for (int g = 0; g < 8; ++g) {
            if (g == i1) continue;
            if (i2 < 0 || acc[g] > acc[i2]) i2 = g;
        }
#pragma unroll
        for (int g = 0; g < 8; ++g) {
            float v = (g == i1 || g == i2) ? (1.f / (1.f + __expf(-acc[g]))) : 0.f;
            w[t * 8 + g] = v;
        }
    }
}

// ---------------------------------------------------------------------------
// Kernel 2: scan — per-expert counts, 128-padded offsets, tile table, row maps
// ---------------------------------------------------------------------------
__global__ __launch_bounds__(1024) void scan_kernel(
    const float* __restrict__ w, int* __restrict__ meta) {
    __shared__ int cnt[8], pos[8];
    const int tid = threadIdx.x;
    if (tid < 8) cnt[tid] = 0;
    __syncthreads();
    for (int t = tid; t < 2048; t += 1024) {
#pragma unroll
        for (int g = 0; g < 8; ++g)
            if (w[t * 8 + g] > 0.f) atomicAdd(&cnt[g], 1);
    }
    __syncthreads();
    if (tid == 0) {
        int base = 0, mt = 0;
        for (int e = 0; e < 8; ++e) {
            pos[e] = base;
            int nt = (cnt[e] + 127) >> 7;
            for (int k = 0; k < nt; ++k) { meta[M_TE + mt] = e; meta[M_TB + mt] = base + k * 128; ++mt; }
            base += nt << 7;
        }
        meta[M_NMT] = mt;
        meta[1] = base;
    }
    __syncthreads();
    for (int i = tid; i < 5120; i += 1024) meta[M_RTOK + i] = -1;
    __syncthreads();
    float* row_w = (float*)&meta[M_RW];
    for (int t = tid; t < 2048; t += 1024) {
        int slot = 0;
#pragma unroll
        for (int g = 0; g < 8; ++g) {
            float wv = w[t * 8 + g];
            if (wv > 0.f) {
                int p = atomicAdd(&pos[g], 1);
                meta[M_RTOK + p] = t;
                row_w[p] = wv;
                meta[M_PAIR + t * 2 + slot] = p;
                ++slot;
            }
        }
    }
}

// ---------------------------------------------------------------------------
// Kernel 3: gather A rows — A[row] = bf16(w_row * h[tok]); pad rows -> 0
// ---------------------------------------------------------------------------
__global__ __launch_bounds__(256) void gather_a_kernel(
    const float* __restrict__ h, const int* __restrict__ meta, u16* __restrict__ A) {
    const int row = blockIdx.x;
    const int tid = threadIdx.x;
    const int tok = meta[M_RTOK + row];
    u16* dst = A + (size_t)row * 1024;
    if (tok < 0) {
        uint2 z; z.x = 0u; z.y = 0u;
        ((uint2*)dst)[tid] = z;
        return;
    }
    const float wv = ((const float*)&meta[M_RW])[row];
    float4 v = ((const float4*)(h + (size_t)tok * 1024))[tid];
    u16 o[4] = { f2bf(v.x * wv), f2bf(v.y * wv), f2bf(v.z * wv), f2bf(v.w * wv) };
    ((uint2*)dst)[tid] = *(const uint2*)o;
}

// ---------------------------------------------------------------------------
// Kernel 4: grouped GEMM1 — up[base..base+128)[4096] = A_rows @ Wi[e]
//   R7-EXACT half-pin (passed, 94.5 µs, VGPR 68). R8's full-pin (32 asm defs)
//   corrupted results — asm-pinned prefetch is only trusted at the verified
//   16-def count. Do not change this kernel without a bisected reason.
// ---------------------------------------------------------------------------
__global__ __launch_bounds__(256) void gemm1_sparse_kernel(
    const u16* __restrict__ A, const float* __restrict__ Wi,
    float* __restrict__ up, const int* __restrict__ meta) {
    const int mt = blockIdx.y;
    if (mt >= meta[M_NMT]) return;
    const int e = meta[M_TE + mt];
    const int base = meta[M_TB + mt];
    const int n0 = blockIdx.x * 128;
    const int K = 1024, N = 4096;
    const float* Bm = Wi + (size_t)e * K * N;

    __shared__ short a_tile[128 * 64];
    __shared__ short b_tile[128 * 64];
    const int tid = threadIdx.x;
    const int lane = tid & 63;
    const int wave = tid >> 6;
    const int wm = (wave >> 1) * 64;
    const int wn = (wave & 1) * 64;
    const int r = lane & 15;
    const int quad = lane >> 4;
    const int rowin = lane >> 3;
    const int achk = ((lane & 7) ^ (rowin & 7)) * 8;   // permuted global chunk
    const int aldst = (lane & 7) * 8;                  // linear LDS chunk

    const int bidx_n = tid & 127;
    const int bidx_k8 = tid >> 7;

    const f32x4 vzero = {0.f, 0.f, 0.f, 0.f};
    f32x4 acc[4][4];
#pragma unroll
    for (int i = 0; i < 4; ++i)
#pragma unroll
        for (int j = 0; j < 4; ++j) acc[i][j] = vzero;

    float bvp[2][8];   // pinned half (k8 groups 0-3), live across compute
    float bvt[2][8];   // transient half (k8 groups 4-7), compiler-placed

    // prologue: pinned half of B(0) via normal loads (latency exposed once)
#pragma unroll
    for (int cb = 0; cb < 2; ++cb) {
        const float* bp = Bm + (size_t)((bidx_k8 + cb * 2) * 8) * N + n0 + bidx_n;
#pragma unroll
        for (int kk = 0; kk < 8; ++kk) bvp[cb][kk] = bp[(size_t)kk * N];
    }

    for (int kb = 0; kb < K; kb += 64) {
        // ---- stage phase ----
#pragma unroll
        for (int it = 0; it < 4; ++it) {
            int row = wave * 8 + it * 32 + rowin;
            const u16* ga = A + (size_t)(base + row) * K + kb + achk;
            __builtin_amdgcn_global_load_lds(GLOBAL_AS(ga), LDS_AS(&a_tile[row * 64 + aldst]), 16, 0, 0);
        }
        // pinned half: values already in regs (drained at prior sync_b)
#pragma unroll
        for (int cb = 0; cb < 2; ++cb) {
            int bk8 = bidx_k8 + cb * 2;
            u16 bc[8];
#pragma unroll
            for (int kk = 0; kk < 8; ++kk) bc[kk] = f2bf(bvp[cb][kk]);
            *(short8_t*)&b_tile[bidx_n * 64 + ((bk8 ^ (bidx_n & 7)) * 8)] = *(const short8_t*)bc;
        }
        // transient half: load now (stage waits on 16 loads, not 32)
#pragma unroll
        for (int cb = 0; cb < 2; ++cb) {
            const float* bp = Bm + (size_t)(kb + (bidx_k8 + (cb + 2) * 2) * 8) * N + n0 + bidx_n;
#pragma unroll
            for (int kk = 0; kk < 8; ++kk) bvt[cb][kk] = bp[(size_t)kk * N];
        }
#pragma unroll
        for (int cb = 0; cb < 2; ++cb) {
            int bk8 = bidx_k8 + (cb + 2) * 2;
            u16 bc[8];
#pragma unroll
            for (int kk = 0; kk < 8; ++kk) bc[kk] = f2bf(bvt[cb][kk]);
            *(short8_t*)&b_tile[bidx_n * 64 + ((bk8 ^ (bidx_n & 7)) * 8)] = *(const short8_t*)bc;
        }
        __syncthreads();   // sync_a: tile (kb) visible

        // ---- pinned issue of next pinned-half (covered by MFMA phase) ----
        if (kb + 64 < K) {
#pragma unroll
            for (int cb = 0; cb < 2; ++cb) {
                const float* bp = Bm + (size_t)(kb + 64 + (bidx_k8 + cb * 2) * 8) * N + n0 + bidx_n;
#pragma unroll
                for (int kk = 0; kk < 8; ++kk) {
                    asm volatile("global_load_dword %0, %1, off"
                                 : "=v"(bvp[cb][kk]) : "v"(bp + (size_t)kk * N));
                }
            }
        }

        // ---- compute phase ----
#pragma unroll
        for (int ks = 0; ks < 2; ++ks) {
            const int cp = ((ks * 4 + quad) ^ (r & 7)) * 8;
            short8_t af[4], bfr[4];
#pragma unroll
            for (int i = 0; i < 4; ++i)
                af[i] = *(const short8_t*)&a_tile[(wm + i * 16 + r) * 64 + cp];
#pragma unroll
            for (int j = 0; j < 4; ++j)
                bfr[j] = *(const short8_t*)&b_tile[(wn + j * 16 + r) * 64 + cp];
#pragma unroll
            for (int i = 0; i < 4; ++i)
#pragma unroll
                for (int j = 0; j < 4; ++j)
                    acc[i][j] = __builtin_amdgcn_mfma_f32_16x16x32_bf16(af[i], bfr[j], acc[i][j], 0, 0, 0);
        }
        __syncthreads();   // sync_b: WAR guard + vmcnt(0) drains pinned loads
    }
    // epilogue: raw fp32 (C/D layout col=lane&15, row=quad*4+reg)
#pragma unroll
    for (int i = 0; i < 4; ++i)
#pragma unroll
        for (int j = 0; j < 4; ++j)
#pragma unroll
            for (int reg = 0; reg < 4; ++reg) {
                int cr = base + wm + i * 16 + quad * 4 + reg;
                int cc = n0 + wn + j * 16 + r;
                up[(size_t)cr * N + cc] = acc[i][j][reg];
            }
}

// ---------------------------------------------------------------------------
// Kernel 5: combine — act[t] = bf16(relu^2(up[p0(t)] + up[p1(t)]))
// ---------------------------------------------------------------------------
__global__ __launch_bounds__(256) void combine_kernel(
    const float* __restrict__ up, const int* __restrict__ meta, u16* __restrict__ act) {
    const int t = blockIdx.x;
    const int tid = threadIdx.x;
    const int p0 = meta[M_PAIR + t * 2];
    const int p1 = meta[M_PAIR + t * 2 + 1];
    const float* r0 = up + (size_t)p0 * 4096;
    const float* r1 = up + (size_t)p1 * 4096;
    u16* dst = act + (size_t)t * 4096;
#pragma unroll
    for (int it = 0; it < 4; ++it) {
        int i = (tid + it * 256) * 4;
        float4 a = *(const float4*)&r0[i];
        float4 b = *(const float4*)&r1[i];
        float s0 = a.x + b.x, s1 = a.y + b.y, s2 = a.z + b.z, s3 = a.w + b.w;
        s0 = s0 > 0.f ? s0 * s0 : 0.f;
        s1 = s1 > 0.f ? s1 * s1 : 0.f;
        s2 = s2 > 0.f ? s2 * s2 : 0.f;
        s3 = s3 > 0.f ? s3 * s3 : 0.f;
        u16 o[4] = { f2bf(s0), f2bf(s1), f2bf(s2), f2bf(s3) };
        *(uint2*)&dst[i] = *(const uint2*)o;
    }
}

// ---------------------------------------------------------------------------
// Kernel 6: GEMM2 NN split-K — P[z][2048][1024] = act[.][kchunk] @ down[kchunk][.]
//   NO inline asm (bisect vs R8 failure): B prefetch via plain C++ loads in
//   the R4-proven position (between sync_a and compute; compiler may sink —
//   correctness-proven schedule). down [4096][1024] fp32 is natural [K][N];
//   B staging = gemm1's reg-roundtrip + f2bf + swizzled store. No transpose.
//   Grid (8 n, 16 m, 4 z) = 512 blocks = 2/CU; m-per-XCD remap.
// ---------------------------------------------------------------------------
__global__ __launch_bounds__(256) void gemm2_nn_kernel(
    const u16* __restrict__ X, const float* __restrict__ B, float* __restrict__ Pout) {
    const int M = 2048, N = 1024, K = 4096;
    const int lid = blockIdx.y * 8 + blockIdx.x;
    const int xcd = lid & 7;
    const int p = lid >> 3;
    const int m_tile = xcd * 2 + (p & 1);   // Mt=16 -> 2 m-tiles per XCD
    const int n_tile = p >> 1;              // Nt=8
    const int m0 = m_tile * 128;
    const int n0 = n_tile * 128;
    const int kb0 = blockIdx.z * 1024;      // kchunk = 1024

    __shared__ short a_tile[128 * 64];
    __shared__ short b_tile[128 * 64];
    const int tid = threadIdx.x;
    const int lane = tid & 63;
    const int wave = tid >> 6;
    const int wm = (wave >> 1) * 64;
    const int wn = (wave & 1) * 64;
    const int r = lane & 15;
    const int quad = lane >> 4;
    const int rowin = lane >> 3;
    const int achk = ((lane & 7) ^ (rowin & 7)) * 8;
    const int aldst = (lane & 7) * 8;

    const int bidx_n = tid & 127;
    const int bidx_k8 = tid >> 7;

    const f32x4 vzero = {0.f, 0.f, 0.f, 0.f};
    f32x4 acc[4][4];
#pragma unroll
    for (int i = 0; i < 4; ++i)
#pragma unroll
        for (int j = 0; j < 4; ++j) acc[i][j] = vzero;

    float bv[4][8];
    // prologue: B(kb0) normal loads (latency exposed once)
#pragma unroll
    for (int cb = 0; cb < 4; ++cb) {
        const float* bp = B + (size_t)(kb0 + (bidx_k8 + cb * 2) * 8) * N + n0 + bidx_n;
#pragma unroll
        for (int kk = 0; kk < 8; ++kk) bv[cb][kk] = bp[(size_t)kk * N];
    }

    for (int kb = 0; kb < 1024; kb += 64) {
        // stage: A async gloads + B reg->LDS (swizzled store)
#pragma unroll
        for (int it = 0; it < 4; ++it) {
            int row = wave * 8 + it * 32 + rowin;
            const u16* ga = X + (size_t)(m0 + row) * K + kb0 + kb + achk;
            __builtin_amdgcn_global_load_lds(GLOBAL_AS(ga), LDS_AS(&a_tile[row * 64 + aldst]), 16, 0, 0);
        }
#pragma unroll
        for (int cb = 0; cb < 4; ++cb) {
            int bk8 = bidx_k8 + cb * 2;
            u16 bc[8];
#pragma unroll
            for (int kk = 0; kk < 8; ++kk) bc[kk] = f2bf(bv[cb][kk]);
            *(short8_t*)&b_tile[bidx_n * 64 + ((bk8 ^ (bidx_n & 7)) * 8)] = *(const short8_t*)bc;
        }
        __syncthreads();   // sync_a

        // issue next B loads before compute (plain C++, R4-proven position)
        if (kb + 64 < 1024) {
#pragma unroll
            for (int cb = 0; cb < 4; ++cb) {
                const float* bp = B + (size_t)(kb0 + kb + 64 + (bidx_k8 + cb * 2) * 8) * N + n0 + bidx_n;
#pragma unroll
                for (int kk = 0; kk < 8; ++kk) bv[cb][kk] = bp[(size_t)kk * N];
            }
        }

        // compute
#pragma unroll
        for (int ks = 0; ks < 2; ++ks) {
            const int cp = ((ks * 4 + quad) ^ (r & 7)) * 8;
            short8_t af[4], bfr[4];
#pragma unroll
            for (int i = 0; i < 4; ++i)
                af[i] = *(const short8_t*)&a_tile[(wm + i * 16 + r) * 64 + cp];
#pragma unroll
            for (int j = 0; j < 4; ++j)
                bfr[j] = *(const short8_t*)&b_tile[(wn + j * 16 + r) * 64 + cp];
#pragma unroll
            for (int i = 0; i < 4; ++i)
#pragma unroll
                for (int j = 0; j < 4; ++j)
                    acc[i][j] = __builtin_amdgcn_mfma_f32_16x16x32_bf16(af[i], bfr[j], acc[i][j], 0, 0, 0);
        }
        __syncthreads();   // sync_b
    }

    float* Co = Pout + (size_t)blockIdx.z * M * N;
#pragma unroll
    for (int i = 0; i < 4; ++i)
#pragma unroll
        for (int j = 0; j < 4; ++j)
#pragma unroll
            for (int reg = 0; reg < 4; ++reg) {
                int cr = m0 + wm + i * 16 + quad * 4 + reg;
                int cc = n0 + wn + j * 16 + r;
                Co[(size_t)cr * N + cc] = acc[i][j][reg];
            }
}

// ---------------------------------------------------------------------------
// Kernel 7: reduce 4 split-K partials -> out
// ---------------------------------------------------------------------------
__global__ __launch_bounds__(256) void reduce4_kernel(
    const float* __restrict__ P, float* __restrict__ out) {
    const size_t S = (size_t)2048 * 1024;
    size_t i = ((size_t)blockIdx.x * 256 + threadIdx.x) * 4;
    float4 a = *(const float4*)&P[i];
    float4 b = *(const float4*)&P[S + i];
    float4 c = *(const float4*)&P[2 * S + i];
    float4 d = *(const float4*)&P[3 * S + i];
    float4 o;
    o.x = (a.x + b.x) + (c.x + d.x);
    o.y = (a.y + b.y) + (c.y + d.y);
    o.z = (a.z + b.z) + (c.z + d.z);
    o.w = (a.w + b.w) + (c.w + d.w);
    *(float4*)&out[i] = o;
}

// ---------------------------------------------------------------------------
// Launch
// ---------------------------------------------------------------------------
extern "C" void kernel_launch(void* const* d_in, const int* in_sizes, int n_in,
                              void* d_out, int out_size, void* d_ws, size_t ws_size,
                              hipStream_t stream) {
    const float* h    = (const float*)d_in[0];   // [2048][1024]
    const float* WG   = (const float*)d_in[1];   // [1024][8]
    const float* Wi   = (const float*)d_in[2];   // [8][1024][4096]
    const float* down = (const float*)d_in[3];   // [4096][1024]
    float* out = (float*)d_out;                  // [2048][1024]

    const int T = 2048;

    // workspace layout (~106 MiB; proven available >= 120.06 MiB)
    char* ws = (char*)d_ws;
    float* w_gate = (float*)(ws);                      // 64 KiB
    int*   meta   = (int*)(ws + 65536);                // 64 KiB
    u16*   Arow   = (u16*)(ws + 131072);               // 5120*1024*2 = 10 MiB
    float* up     = (float*)(ws + 131072 + 10485760);  // 5120*4096*4 = 80 MiB
    u16*   act    = (u16*)(ws + 131072 + 10485760 + 83886080);   // 16 MiB
    // split-K partials (4 x 8 MiB = 32 MiB) reuse the up region: combine has
    // already consumed up before gemm2 runs (stream-ordered).
    float* part   = up;

    gate_topk_kernel<<<T, 64, 0, stream>>>(h, WG, w_gate);
    scan_kernel<<<1, 1024, 0, stream>>>(w_gate, meta);
    gather_a_kernel<<<5120, 256, 0, stream>>>(h, meta, Arow);

    // grouped GEMM1: up to 40 m-tiles x 32 n-tiles; raw fp32 out
    gemm1_sparse_kernel<<<dim3(32, 40), 256, 0, stream>>>(Arow, Wi, up, meta);

    // combine pairs + relu^2 -> dense act bf16 [2048][4096]
    combine_kernel<<<T, 256, 0, stream>>>(up, meta, act);

    // GEMM2 NN split-K=4 directly on down [4096][1024] (no transpose) -> reduce
    gemm2_nn_kernel<<<dim3(8, 16, 4), 256, 0, stream>>>(act, down, part);
    reduce4_kernel<<<(T * 1024) / 1024, 256, 0, stream>>>(part, out);
}

// Round 10
// 334.163 us; speedup vs baseline: 1.0196x; 1.0196x over previous
//
#include <hip/hip_runtime.h>
#include <hip/hip_bf16.h>

typedef unsigned short u16;
typedef short short8_t __attribute__((ext_vector_type(8)));
typedef float f32x4 __attribute__((ext_vector_type(4)));

#define GLOBAL_AS(p) ((const __attribute__((address_space(1))) void*)(p))
#define LDS_AS(p)    ((__attribute__((address_space(3))) void*)(p))

__device__ __forceinline__ u16 f2bf(float f) {
    union { float f; unsigned int u; } x;
    x.f = f;
    unsigned int r = x.u + 0x7fffu + ((x.u >> 16) & 1u);   // RNE
    return (u16)(r >> 16);
}

// meta layout (ints), fits in 64 KiB:
//  [0] n_mtiles   [1] total_padded_rows
//  [2..42)   tile_expert
//  [42..82)  tile_base_row
//  [96..96+4096)   pair_row[t*2+j]  (row index of token t's j-th expert)
//  [4192..9312)    row_tok[row]     (token id, -1 = pad)
//  [9312..14432)   row_w[row]       (float weight)
#define M_NMT   0
#define M_TE    2
#define M_TB    42
#define M_PAIR  96
#define M_RTOK  4192
#define M_RW    9312

// ---------------------------------------------------------------------------
// Kernel 1: gate = h @ WG, top-2 sigmoid weights -> w[2048][8] fp32
// ---------------------------------------------------------------------------
__global__ __launch_bounds__(64) void gate_topk_kernel(
    const float* __restrict__ h, const float* __restrict__ wg, float* __restrict__ w) {
    const int t = blockIdx.x;
    const int lane = threadIdx.x;
    float acc[8];
#pragma unroll
    for (int g = 0; g < 8; ++g) acc[g] = 0.f;
    for (int e = lane; e < 1024; e += 64) {
        float hv = h[(size_t)t * 1024 + e];
        float4 r0 = *(const float4*)&wg[e * 8];
        float4 r1 = *(const float4*)&wg[e * 8 + 4];
        acc[0] += hv * r0.x; acc[1] += hv * r0.y; acc[2] += hv * r0.z; acc[3] += hv * r0.w;
        acc[4] += hv * r1.x; acc[5] += hv * r1.y; acc[6] += hv * r1.z; acc[7] += hv * r1.w;
    }
#pragma unroll
    for (int off = 32; off > 0; off >>= 1) {
#pragma unroll
        for (int g = 0; g < 8; ++g) acc[g] += __shfl_down(acc[g], off);
    }
    if (lane == 0) {
        int i1 = 0;
        for (int g = 1; g < 8; ++g) if (acc[g] > acc[i1]) i1 = g;   // lowest idx on ties
        int i2 = -1;
        for (int g = 0; g < 8; ++g) {
            if (g == i1) continue;
            if (i2 < 0 || acc[g] > acc[i2]) i2 = g;
        }
#pragma unroll
        for (int g = 0; g < 8; ++g) {
            float v = (g == i1 || g == i2) ? (1.f / (1.f + __expf(-acc[g]))) : 0.f;
            w[t * 8 + g] = v;
        }
    }
}

// ---------------------------------------------------------------------------
// Kernel 2: scan — ballot/popcount version (zero atomics).
// Old version: 16K shared atomicAdds on 8 counters = max same-address
// contention, hardware-serialized. New: per-wave per-expert __ballot ->
// popcount counts -> tiny serial prefix -> rank = popc(mask & lt).
// Row assignment is a different (deterministic) bijection — semantics
// identical (combine only sums the pair; order within expert irrelevant).
// ---------------------------------------------------------------------------
__global__ __launch_bounds__(1024) void scan_kernel(
    const float* __restrict__ w, int* __restrict__ meta) {
    __shared__ int wcnt[2][16][8];
    __shared__ int woff[2][16][8];
    __shared__ int ebase[8];
    const int tid = threadIdx.x;
    const int wv = tid >> 6;
    const int ln = tid & 63;
    const unsigned long long ltmask = (1ull << ln) - 1ull;

    // zero row_tok region in parallel (completes before assignment: barriers below)
    for (int i = tid; i < 5120; i += 1024) meta[M_RTOK + i] = -1;

    unsigned long long msk[2][8];
#pragma unroll
    for (int p = 0; p < 2; ++p) {
        const int t = tid + p * 1024;
#pragma unroll
        for (int g = 0; g < 8; ++g) {
            const bool f = w[t * 8 + g] > 0.f;
            msk[p][g] = __ballot(f);
        }
        if (ln == 0) {
#pragma unroll
            for (int g = 0; g < 8; ++g) wcnt[p][wv][g] = __popcll(msk[p][g]);
        }
    }
    __syncthreads();
    if (tid == 0) {
        int cnt[8];
        for (int g = 0; g < 8; ++g) {
            int s = 0;
            for (int p = 0; p < 2; ++p)
                for (int v = 0; v < 16; ++v) s += wcnt[p][v][g];
            cnt[g] = s;
        }
        int base = 0, mt = 0;
        for (int e = 0; e < 8; ++e) {
            ebase[e] = base;
            int nt = (cnt[e] + 127) >> 7;
            for (int k = 0; k < nt; ++k) { meta[M_TE + mt] = e; meta[M_TB + mt] = base + k * 128; ++mt; }
            base += nt << 7;
        }
        meta[M_NMT] = mt;
        meta[1] = base;
    }
    __syncthreads();
    if (tid < 8) {
        const int g = tid;
        int run = ebase[g];
        for (int p = 0; p < 2; ++p)
            for (int v = 0; v < 16; ++v) { woff[p][v][g] = run; run += wcnt[p][v][g]; }
    }
    __syncthreads();
    float* row_w = (float*)&meta[M_RW];
#pragma unroll
    for (int p = 0; p < 2; ++p) {
        const int t = tid + p * 1024;
        int slot = 0;
#pragma unroll
        for (int g = 0; g < 8; ++g) {
            const float wval = w[t * 8 + g];
            if (wval > 0.f) {
                const int row = woff[p][wv][g] + __popcll(msk[p][g] & ltmask);
                meta[M_RTOK + row] = t;
                row_w[row] = wval;
                meta[M_PAIR + t * 2 + slot] = row;
                ++slot;
            }
        }
    }
}

// ---------------------------------------------------------------------------
// Kernel 3: gather A rows — A[row] = bf16(w_row * h[tok]); pad rows -> 0
// ---------------------------------------------------------------------------
__global__ __launch_bounds__(256) void gather_a_kernel(
    const float* __restrict__ h, const int* __restrict__ meta, u16* __restrict__ A) {
    const int row = blockIdx.x;
    const int tid = threadIdx.x;
    const int tok = meta[M_RTOK + row];
    u16* dst = A + (size_t)row * 1024;
    if (tok < 0) {
        uint2 z; z.x = 0u; z.y = 0u;
        ((uint2*)dst)[tid] = z;
        return;
    }
    const float wv = ((const float*)&meta[M_RW])[row];
    float4 v = ((const float4*)(h + (size_t)tok * 1024))[tid];
    u16 o[4] = { f2bf(v.x * wv), f2bf(v.y * wv), f2bf(v.z * wv), f2bf(v.w * wv) };
    ((uint2*)dst)[tid] = *(const uint2*)o;
}

// ---------------------------------------------------------------------------
// Kernel 4: grouped GEMM1 — up[base..base+128)[4096] = A_rows @ Wi[e]
//   R7-EXACT half-pin (passed R7+R9, 94.5 µs, VGPR 68). Full-pin (32 asm
//   defs) corrupts (R8). Do not change without a bisected reason.
// ---------------------------------------------------------------------------
__global__ __launch_bounds__(256) void gemm1_sparse_kernel(
    const u16* __restrict__ A, const float* __restrict__ Wi,
    float* __restrict__ up, const int* __restrict__ meta) {
    const int mt = blockIdx.y;
    if (mt >= meta[M_NMT]) return;
    const int e = meta[M_TE + mt];
    const int base = meta[M_TB + mt];
    const int n0 = blockIdx.x * 128;
    const int K = 1024, N = 4096;
    const float* Bm = Wi + (size_t)e * K * N;

    __shared__ short a_tile[128 * 64];
    __shared__ short b_tile[128 * 64];
    const int tid = threadIdx.x;
    const int lane = tid & 63;
    const int wave = tid >> 6;
    const int wm = (wave >> 1) * 64;
    const int wn = (wave & 1) * 64;
    const int r = lane & 15;
    const int quad = lane >> 4;
    const int rowin = lane >> 3;
    const int achk = ((lane & 7) ^ (rowin & 7)) * 8;   // permuted global chunk
    const int aldst = (lane & 7) * 8;                  // linear LDS chunk

    const int bidx_n = tid & 127;
    const int bidx_k8 = tid >> 7;

    const f32x4 vzero = {0.f, 0.f, 0.f, 0.f};
    f32x4 acc[4][4];
#pragma unroll
    for (int i = 0; i < 4; ++i)
#pragma unroll
        for (int j = 0; j < 4; ++j) acc[i][j] = vzero;

    float bvp[2][8];   // pinned half (k8 groups 0-3), live across compute
    float bvt[2][8];   // transient half (k8 groups 4-7), compiler-placed

    // prologue: pinned half of B(0) via normal loads (latency exposed once)
#pragma unroll
    for (int cb = 0; cb < 2; ++cb) {
        const float* bp = Bm + (size_t)((bidx_k8 + cb * 2) * 8) * N + n0 + bidx_n;
#pragma unroll
        for (int kk = 0; kk < 8; ++kk) bvp[cb][kk] = bp[(size_t)kk * N];
    }

    for (int kb = 0; kb < K; kb += 64) {
        // ---- stage phase ----
#pragma unroll
        for (int it = 0; it < 4; ++it) {
            int row = wave * 8 + it * 32 + rowin;
            const u16* ga = A + (size_t)(base + row) * K + kb + achk;
            __builtin_amdgcn_global_load_lds(GLOBAL_AS(ga), LDS_AS(&a_tile[row * 64 + aldst]), 16, 0, 0);
        }
        // pinned half: values already in regs (drained at prior sync_b)
#pragma unroll
        for (int cb = 0; cb < 2; ++cb) {
            int bk8 = bidx_k8 + cb * 2;
            u16 bc[8];
#pragma unroll
            for (int kk = 0; kk < 8; ++kk) bc[kk] = f2bf(bvp[cb][kk]);
            *(short8_t*)&b_tile[bidx_n * 64 + ((bk8 ^ (bidx_n & 7)) * 8)] = *(const short8_t*)bc;
        }
        // transient half: load now (stage waits on 16 loads, not 32)
#pragma unroll
        for (int cb = 0; cb < 2; ++cb) {
            const float* bp = Bm + (size_t)(kb + (bidx_k8 + (cb + 2) * 2) * 8) * N + n0 + bidx_n;
#pragma unroll
            for (int kk = 0; kk < 8; ++kk) bvt[cb][kk] = bp[(size_t)kk * N];
        }
#pragma unroll
        for (int cb = 0; cb < 2; ++cb) {
            int bk8 = bidx_k8 + (cb + 2) * 2;
            u16 bc[8];
#pragma unroll
            for (int kk = 0; kk < 8; ++kk) bc[kk] = f2bf(bvt[cb][kk]);
            *(short8_t*)&b_tile[bidx_n * 64 + ((bk8 ^ (bidx_n & 7)) * 8)] = *(const short8_t*)bc;
        }
        __syncthreads();   // sync_a: tile (kb) visible

        // ---- pinned issue of next pinned-half (covered by MFMA phase) ----
        if (kb + 64 < K) {
#pragma unroll
            for (int cb = 0; cb < 2; ++cb) {
                const float* bp = Bm + (size_t)(kb + 64 + (bidx_k8 + cb * 2) * 8) * N + n0 + bidx_n;
#pragma unroll
                for (int kk = 0; kk < 8; ++kk) {
                    asm volatile("global_load_dword %0, %1, off"
                                 : "=v"(bvp[cb][kk]) : "v"(bp + (size_t)kk * N));
                }
            }
        }

        // ---- compute phase ----
#pragma unroll
        for (int ks = 0; ks < 2; ++ks) {
            const int cp = ((ks * 4 + quad) ^ (r & 7)) * 8;
            short8_t af[4], bfr[4];
#pragma unroll
            for (int i = 0; i < 4; ++i)
                af[i] = *(const short8_t*)&a_tile[(wm + i * 16 + r) * 64 + cp];
#pragma unroll
            for (int j = 0; j < 4; ++j)
                bfr[j] = *(const short8_t*)&b_tile[(wn + j * 16 + r) * 64 + cp];
#pragma unroll
            for (int i = 0; i < 4; ++i)
#pragma unroll
                for (int j = 0; j < 4; ++j)
                    acc[i][j] = __builtin_amdgcn_mfma_f32_16x16x32_bf16(af[i], bfr[j], acc[i][j], 0, 0, 0);
        }
        __syncthreads();   // sync_b: WAR guard + vmcnt(0) drains pinned loads
    }
    // epilogue: raw fp32 (C/D layout col=lane&15, row=quad*4+reg)
#pragma unroll
    for (int i = 0; i < 4; ++i)
#pragma unroll
        for (int j = 0; j < 4; ++j)
#pragma unroll
            for (int reg = 0; reg < 4; ++reg) {
                int cr = base + wm + i * 16 + quad * 4 + reg;
                int cc = n0 + wn + j * 16 + r;
                up[(size_t)cr * N + cc] = acc[i][j][reg];
            }
}

// ---------------------------------------------------------------------------
// Kernel 5: combine — act[t] = bf16(relu^2(up[p0(t)] + up[p1(t)]))
// ---------------------------------------------------------------------------
__global__ __launch_bounds__(256) void combine_kernel(
    const float* __restrict__ up, const int* __restrict__ meta, u16* __restrict__ act) {
    const int t = blockIdx.x;
    const int tid = threadIdx.x;
    const int p0 = meta[M_PAIR + t * 2];
    const int p1 = meta[M_PAIR + t * 2 + 1];
    const float* r0 = up + (size_t)p0 * 4096;
    const float* r1 = up + (size_t)p1 * 4096;
    u16* dst = act + (size_t)t * 4096;
#pragma unroll
    for (int it = 0; it < 4; ++it) {
        int i = (tid + it * 256) * 4;
        float4 a = *(const float4*)&r0[i];
        float4 b = *(const float4*)&r1[i];
        float s0 = a.x + b.x, s1 = a.y + b.y, s2 = a.z + b.z, s3 = a.w + b.w;
        s0 = s0 > 0.f ? s0 * s0 : 0.f;
        s1 = s1 > 0.f ? s1 * s1 : 0.f;
        s2 = s2 > 0.f ? s2 * s2 : 0.f;
        s3 = s3 > 0.f ? s3 * s3 : 0.f;
        u16 o[4] = { f2bf(s0), f2bf(s1), f2bf(s2), f2bf(s3) };
        *(uint2*)&dst[i] = *(const uint2*)o;
    }
}

// ---------------------------------------------------------------------------
// Kernel T: transpose + fp32->bf16  in[R][C] fp32 -> out[C][R] bf16
// ---------------------------------------------------------------------------
__global__ __launch_bounds__(256) void transpose_cvt_kernel(
    const float* __restrict__ in, u16* __restrict__ out, int R, int C) {
    __shared__ u16 tile[64][65];
    const int rt = blockIdx.y * 64;
    const int ct = blockIdx.x * 64;
    const int tid = threadIdx.x;
#pragma unroll
    for (int it = 0; it < 2; ++it) {
        int r = (tid >> 3) + it * 32;
        int c8 = (tid & 7) * 8;
        const float* ip = &in[(size_t)(rt + r) * C + ct + c8];
        float4 v0 = *(const float4*)ip;
        float4 v1 = *(const float4*)(ip + 4);
        tile[c8 + 0][r] = f2bf(v0.x); tile[c8 + 1][r] = f2bf(v0.y);
        tile[c8 + 2][r] = f2bf(v0.z); tile[c8 + 3][r] = f2bf(v0.w);
        tile[c8 + 4][r] = f2bf(v1.x); tile[c8 + 5][r] = f2bf(v1.y);
        tile[c8 + 6][r] = f2bf(v1.z); tile[c8 + 7][r] = f2bf(v1.w);
    }
    __syncthreads();
#pragma unroll
    for (int it = 0; it < 2; ++it) {
        int c = (tid >> 3) + it * 32;
        int r8 = (tid & 7) * 8;
        u16 tmp[8];
#pragma unroll
        for (int j = 0; j < 8; ++j) tmp[j] = tile[c][r8 + j];
        *(uint4*)&out[(size_t)(ct + c) * R + rt + r8] = *(const uint4*)tmp;
    }
}

// ---------------------------------------------------------------------------
// Kernel 6: GEMM2 TN split-K — P[z][M][N] = X[M][kchunk] @ Y^T[kchunk]
// R7-exact: both operands bf16 [row][K], all staging via async gload_lds,
// dbuf 2-phase; BM=128 x 4 K-chunks = 512 blocks = 2/CU; m-per-XCD remap.
// (R9 proved NN reg-roundtrip staging is ~6 µs slower than transpose+TN.)
// ---------------------------------------------------------------------------
template <int BM, int WROWS, int WCOLS>
__global__ __launch_bounds__(256) void gemm_tn_kernel(
    const u16* __restrict__ X, const u16* __restrict__ Y, float* __restrict__ Pout,
    int M, int N, int K) {
    constexpr int WM = BM / WROWS;
    constexpr int WN = 128 / WCOLS;
    constexpr int FI = WM / 16;
    constexpr int FJ = WN / 16;
    __shared__ short a_tile[2][BM * 64];
    __shared__ short b_tile[2][128 * 64];
    const int tid = threadIdx.x;
    const int lane = tid & 63;
    const int wave = tid >> 6;

    // XCD-aware remap: same m_tile group -> same XCD (X reuse is 8-way).
    const int Nt = gridDim.x, Mt = gridDim.y;
    const int lid = blockIdx.y * Nt + blockIdx.x;
    const int xcd = lid & 7;
    const int p = lid >> 3;
    const int mpx = Mt >> 3;                 // m-tiles per XCD (16/8 = 2)
    const int m_tile = xcd * mpx + (p % mpx);
    const int n_tile = p / mpx;
    const int m0 = m_tile * BM;
    const int n0 = n_tile * 128;
    const int kchunk = K >> 2;               // gridDim.z == 4
    const int kb0 = blockIdx.z * kchunk;

    const int wm = (wave / WCOLS) * WM;
    const int wn = (wave % WCOLS) * WN;
    const int rowin = lane >> 3;
    const int achk = ((lane & 7) ^ (rowin & 7)) * 8;
    const int aldst = (lane & 7) * 8;
    const int r = lane & 15;
    const int quad = lane >> 4;

    const f32x4 vzero = {0.f, 0.f, 0.f, 0.f};
    f32x4 acc[FI][FJ];
#pragma unroll
    for (int i = 0; i < FI; ++i)
#pragma unroll
        for (int j = 0; j < FJ; ++j) acc[i][j] = vzero;

#define G2_STAGE(kb_, buf)                                                            \
    {                                                                                 \
        const int kbc = (kb_);                                                        \
        _Pragma("unroll")                                                             \
        for (int it = 0; it < BM / 32; ++it) {                                        \
            int row = wave * 8 + it * 32 + rowin;                                     \
            const u16* ga = X + (size_t)(m0 + row) * K + kbc + achk;                  \
            __builtin_amdgcn_global_load_lds(GLOBAL_AS(ga),                           \
                LDS_AS(&a_tile[buf][row * 64 + aldst]), 16, 0, 0);                    \
        }                                                                             \
        _Pragma("unroll")                                                             \
        for (int it = 0; it < 4; ++it) {                                              \
            int row = wave * 8 + it * 32 + rowin;                                     \
            const u16* gb = Y + (size_t)(n0 + row) * K + kbc + achk;                  \
            __builtin_amdgcn_global_load_lds(GLOBAL_AS(gb),                           \
                LDS_AS(&b_tile[buf][row * 64 + aldst]), 16, 0, 0);                    \
        }                                                                             \
    }

#define G2_COMPUTE(buf)                                                               \
    {                                                                                 \
        _Pragma("unroll")                                                             \
        for (int ks = 0; ks < 2; ++ks) {                                              \
            const int cp = ((ks * 4 + quad) ^ (r & 7)) * 8;                           \
            short8_t af[FI], bfr[FJ];                                                 \
            _Pragma("unroll")                                                         \
            for (int i = 0; i < FI; ++i)                                              \
                af[i] = *(const short8_t*)&a_tile[buf][(wm + i * 16 + r) * 64 + cp];  \
            _Pragma("unroll")                                                         \
            for (int j = 0; j < FJ; ++j)                                              \
                bfr[j] = *(const short8_t*)&b_tile[buf][(wn + j * 16 + r) * 64 + cp]; \
            _Pragma("unroll")                                                         \
            for (int i = 0; i < FI; ++i)                                              \
                _Pragma("unroll")                                                     \
                for (int j = 0; j < FJ; ++j)                                          \
                    acc[i][j] = __builtin_amdgcn_mfma_f32_16x16x32_bf16(              \
                        af[i], bfr[j], acc[i][j], 0, 0, 0);                           \
        }                                                                             \
    }

    const int nk = kchunk >> 6;
    G2_STAGE(kb0, 0);
    __syncthreads();
    for (int t = 0; t < nk - 1; ++t) {
        const int nxt = (t + 1) & 1;
        G2_STAGE(kb0 + (t + 1) * 64, nxt);
        G2_COMPUTE(t & 1);
        __syncthreads();
    }
    G2_COMPUTE((nk - 1) & 1);

#undef G2_STAGE
#undef G2_COMPUTE

    float* Co = Pout + (size_t)blockIdx.z * M * N;
#pragma unroll
    for (int i = 0; i < FI; ++i)
#pragma unroll
        for (int j = 0; j < FJ; ++j)
#pragma unroll
            for (int reg = 0; reg < 4; ++reg) {
                int cr = m0 + wm + i * 16 + quad * 4 + reg;
                int cc = n0 + wn + j * 16 + r;
                Co[(size_t)cr * N + cc] = acc[i][j][reg];
            }
}

// ---------------------------------------------------------------------------
// Kernel 7: reduce 4 split-K partials -> out
// ---------------------------------------------------------------------------
__global__ __launch_bounds__(256) void reduce4_kernel(
    const float* __restrict__ P, float* __restrict__ out) {
    const size_t S = (size_t)2048 * 1024;
    size_t i = ((size_t)blockIdx.x * 256 + threadIdx.x) * 4;
    float4 a = *(const float4*)&P[i];
    float4 b = *(const float4*)&P[S + i];
    float4 c = *(const float4*)&P[2 * S + i];
    float4 d = *(const float4*)&P[3 * S + i];
    float4 o;
    o.x = (a.x + b.x) + (c.x + d.x);
    o.y = (a.y + b.y) + (c.y + d.y);
    o.z = (a.z + b.z) + (c.z + d.z);
    o.w = (a.w + b.w) + (c.w + d.w);
    *(float4*)&out[i] = o;
}

// ---------------------------------------------------------------------------
// Launch
// ---------------------------------------------------------------------------
extern "C" void kernel_launch(void* const* d_in, const int* in_sizes, int n_in,
                              void* d_out, int out_size, void* d_ws, size_t ws_size,
                              hipStream_t stream) {
    const float* h    = (const float*)d_in[0];   // [2048][1024]
    const float* WG   = (const float*)d_in[1];   // [1024][8]
    const float* Wi   = (const float*)d_in[2];   // [8][1024][4096]
    const float* down = (const float*)d_in[3];   // [4096][1024]
    float* out = (float*)d_out;                  // [2048][1024]

    const int T = 2048, H = 1024, I = 4096;

    // workspace layout (~114.1 MiB; proven available >= 120.06 MiB)
    char* ws = (char*)d_ws;
    float* w_gate = (float*)(ws);                      // 64 KiB
    int*   meta   = (int*)(ws + 65536);                // 64 KiB
    u16*   Arow   = (u16*)(ws + 131072);               // 5120*1024*2 = 10 MiB
    float* up     = (float*)(ws + 131072 + 10485760);  // 5120*4096*4 = 80 MiB
    u16*   act    = (u16*)(ws + 131072 + 10485760 + 83886080);            // 16 MiB
    u16*   downT  = (u16*)(ws + 131072 + 10485760 + 83886080 + 16777216); // 8 MiB
    // split-K partials (4 x 8 MiB = 32 MiB) reuse the up region: combine has
    // already consumed up before gemm2 runs (stream-ordered).
    float* part   = up;

    gate_topk_kernel<<<T, 64, 0, stream>>>(h, WG, w_gate);
    scan_kernel<<<1, 1024, 0, stream>>>(w_gate, meta);
    gather_a_kernel<<<5120, 256, 0, stream>>>(h, meta, Arow);

    // grouped GEMM1: up to 40 m-tiles x 32 n-tiles; raw fp32 out
    gemm1_sparse_kernel<<<dim3(32, 40), 256, 0, stream>>>(Arow, Wi, up, meta);

    // combine pairs + relu^2 -> dense act bf16 [2048][4096]
    combine_kernel<<<T, 256, 0, stream>>>(up, meta, act);

    // down^T bf16, then GEMM2 TN split-K=4 -> partials -> reduce -> out
    transpose_cvt_kernel<<<dim3(H / 64, I / 64), 256, 0, stream>>>(down, downT, I, H);
    gemm_tn_kernel<128, 2, 2><<<dim3(H / 128, T / 128, 4), 256, 0, stream>>>(
        act, downT, part, T, H, I);
    reduce4_kernel<<<(T * H) / 1024, 256, 0, stream>>>(part, out);
}

// Round 11
// 328.259 us; speedup vs baseline: 1.0379x; 1.0180x over previous
//
#include <hip/hip_runtime.h>
#include <hip/hip_bf16.h>

typedef unsigned short u16;
typedef short short8_t __attribute__((ext_vector_type(8)));
typedef float f32x4 __attribute__((ext_vector_type(4)));

#define GLOBAL_AS(p) ((const __attribute__((address_space(1))) void*)(p))
#define LDS_AS(p)    ((__attribute__((address_space(3))) void*)(p))

__device__ __forceinline__ u16 f2bf(float f) {
    union { float f; unsigned int u; } x;
    x.f = f;
    unsigned int r = x.u + 0x7fffu + ((x.u >> 16) & 1u);   // RNE
    return (u16)(r >> 16);
}
__device__ __forceinline__ float bf2f(u16 v) {
    union { unsigned int u; float f; } x;
    x.u = ((unsigned int)v) << 16;
    return x.f;
}

// meta layout (ints), fits in 64 KiB:
//  [0] n_mtiles   [1] total_padded_rows
//  [2..42)   tile_expert
//  [42..82)  tile_base_row
//  [96..96+4096)   pair_row[t*2+j]  (row index of token t's j-th expert)
//  [4192..9312)    row_tok[row]     (token id, -1 = pad)
//  [9312..14432)   row_w[row]       (float weight)
#define M_NMT   0
#define M_TE    2
#define M_TB    42
#define M_PAIR  96
#define M_RTOK  4192
#define M_RW    9312

// ---------------------------------------------------------------------------
// Kernel 1: gate = h @ WG, top-2 sigmoid weights -> w[2048][8] fp32
// ---------------------------------------------------------------------------
__global__ __launch_bounds__(64) void gate_topk_kernel(
    const float* __restrict__ h, const float* __restrict__ wg, float* __restrict__ w) {
    const int t = blockIdx.x;
    const int lane = threadIdx.x;
    float acc[8];
#pragma unroll
    for (int g = 0; g < 8; ++g) acc[g] = 0.f;
    for (int e = lane; e < 1024; e += 64) {
        float hv = h[(size_t)t * 1024 + e];
        float4 r0 = *(const float4*)&wg[e * 8];
        float4 r1 = *(const float4*)&wg[e * 8 + 4];
        acc[0] += hv * r0.x; acc[1] += hv * r0.y; acc[2] += hv * r0.z; acc[3] += hv * r0.w;
        acc[4] += hv * r1.x; acc[5] += hv * r1.y; acc[6] += hv * r1.z; acc[7] += hv * r1.w;
    }
#pragma unroll
    for (int off = 32; off > 0; off >>= 1) {
#pragma unroll
        for (int g = 0; g < 8; ++g) acc[g] += __shfl_down(acc[g], off);
    }
    if (lane == 0) {
        int i1 = 0;
        for (int g = 1; g < 8; ++g) if (acc[g] > acc[i1]) i1 = g;   // lowest idx on ties
        int i2 = -1;
        for (int g = 0; g < 8; ++g) {
            if (g == i1) continue;
            if (i2 < 0 || acc[g] > acc[i2]) i2 = g;
        }
#pragma unroll
        for (int g = 0; g < 8; ++g) {
            float v = (g == i1 || g == i2) ? (1.f / (1.f + __expf(-acc[g]))) : 0.f;
            w[t * 8 + g] = v;
        }
    }
}

// ---------------------------------------------------------------------------
// Kernel 2: scan — ballot/popcount (zero atomics, R10-verified)
// ---------------------------------------------------------------------------
__global__ __launch_bounds__(1024) void scan_kernel(
    const float* __restrict__ w, int* __restrict__ meta) {
    __shared__ int wcnt[2][16][8];
    __shared__ int woff[2][16][8];
    __shared__ int ebase[8];
    const int tid = threadIdx.x;
    const int wv = tid >> 6;
    const int ln = tid & 63;
    const unsigned long long ltmask = (1ull << ln) - 1ull;

    for (int i = tid; i < 5120; i += 1024) meta[M_RTOK + i] = -1;

    unsigned long long msk[2][8];
#pragma unroll
    for (int p = 0; p < 2; ++p) {
        const int t = tid + p * 1024;
#pragma unroll
        for (int g = 0; g < 8; ++g) {
            const bool f = w[t * 8 + g] > 0.f;
            msk[p][g] = __ballot(f);
        }
        if (ln == 0) {
#pragma unroll
            for (int g = 0; g < 8; ++g) wcnt[p][wv][g] = __popcll(msk[p][g]);
        }
    }
    __syncthreads();
    if (tid == 0) {
        int cnt[8];
        for (int g = 0; g < 8; ++g) {
            int s = 0;
            for (int p = 0; p < 2; ++p)
                for (int v = 0; v < 16; ++v) s += wcnt[p][v][g];
            cnt[g] = s;
        }
        int base = 0, mt = 0;
        for (int e = 0; e < 8; ++e) {
            ebase[e] = base;
            int nt = (cnt[e] + 127) >> 7;
            for (int k = 0; k < nt; ++k) { meta[M_TE + mt] = e; meta[M_TB + mt] = base + k * 128; ++mt; }
            base += nt << 7;
        }
        meta[M_NMT] = mt;
        meta[1] = base;
    }
    __syncthreads();
    if (tid < 8) {
        const int g = tid;
        int run = ebase[g];
        for (int p = 0; p < 2; ++p)
            for (int v = 0; v < 16; ++v) { woff[p][v][g] = run; run += wcnt[p][v][g]; }
    }
    __syncthreads();
    float* row_w = (float*)&meta[M_RW];
#pragma unroll
    for (int p = 0; p < 2; ++p) {
        const int t = tid + p * 1024;
        int slot = 0;
#pragma unroll
        for (int g = 0; g < 8; ++g) {
            const float wval = w[t * 8 + g];
            if (wval > 0.f) {
                const int row = woff[p][wv][g] + __popcll(msk[p][g] & ltmask);
                meta[M_RTOK + row] = t;
                row_w[row] = wval;
                meta[M_PAIR + t * 2 + slot] = row;
                ++slot;
            }
        }
    }
}

// ---------------------------------------------------------------------------
// Kernel 3: gather A rows — A[row] = bf16(w_row * h[tok]); pad rows -> 0
// ---------------------------------------------------------------------------
__global__ __launch_bounds__(256) void gather_a_kernel(
    const float* __restrict__ h, const int* __restrict__ meta, u16* __restrict__ A) {
    const int row = blockIdx.x;
    const int tid = threadIdx.x;
    const int tok = meta[M_RTOK + row];
    u16* dst = A + (size_t)row * 1024;
    if (tok < 0) {
        uint2 z; z.x = 0u; z.y = 0u;
        ((uint2*)dst)[tid] = z;
        return;
    }
    const float wv = ((const float*)&meta[M_RW])[row];
    float4 v = ((const float4*)(h + (size_t)tok * 1024))[tid];
    u16 o[4] = { f2bf(v.x * wv), f2bf(v.y * wv), f2bf(v.z * wv), f2bf(v.w * wv) };
    ((uint2*)dst)[tid] = *(const uint2*)o;
}

// ---------------------------------------------------------------------------
// Kernel 4: grouped GEMM1 — up[base..base+128)[4096] = A_rows @ Wi[e]
//   R7-EXACT half-pin schedule (R7/R9/R10-verified, ~95 µs, VGPR 68).
//   ONLY change this round: epilogue writes up as BF16 (u16) — halves
//   WRITE_SIZE (73.7 -> ~37 MB) and combine's read. relu^2 still happens
//   after the cross-expert fp32 sum in combine; bf16 rounding of partials
//   adds ~0.01 absmax (margin: 0.0625 vs 0.195 threshold).
// ---------------------------------------------------------------------------
__global__ __launch_bounds__(256) void gemm1_sparse_kernel(
    const u16* __restrict__ A, const float* __restrict__ Wi,
    u16* __restrict__ up, const int* __restrict__ meta) {
    const int mt = blockIdx.y;
    if (mt >= meta[M_NMT]) return;
    const int e = meta[M_TE + mt];
    const int base = meta[M_TB + mt];
    const int n0 = blockIdx.x * 128;
    const int K = 1024, N = 4096;
    const float* Bm = Wi + (size_t)e * K * N;

    __shared__ short a_tile[128 * 64];
    __shared__ short b_tile[128 * 64];
    const int tid = threadIdx.x;
    const int lane = tid & 63;
    const int wave = tid >> 6;
    const int wm = (wave >> 1) * 64;
    const int wn = (wave & 1) * 64;
    const int r = lane & 15;
    const int quad = lane >> 4;
    const int rowin = lane >> 3;
    const int achk = ((lane & 7) ^ (rowin & 7)) * 8;   // permuted global chunk
    const int aldst = (lane & 7) * 8;                  // linear LDS chunk

    const int bidx_n = tid & 127;
    const int bidx_k8 = tid >> 7;

    const f32x4 vzero = {0.f, 0.f, 0.f, 0.f};
    f32x4 acc[4][4];
#pragma unroll
    for (int i = 0; i < 4; ++i)
#pragma unroll
        for (int j = 0; j < 4; ++j) acc[i][j] = vzero;

    float bvp[2][8];   // pinned half (k8 groups 0-3), live across compute
    float bvt[2][8];   // transient half (k8 groups 4-7), compiler-placed

    // prologue: pinned half of B(0) via normal loads (latency exposed once)
#pragma unroll
    for (int cb = 0; cb < 2; ++cb) {
        const float* bp = Bm + (size_t)((bidx_k8 + cb * 2) * 8) * N + n0 + bidx_n;
#pragma unroll
        for (int kk = 0; kk < 8; ++kk) bvp[cb][kk] = bp[(size_t)kk * N];
    }

    for (int kb = 0; kb < K; kb += 64) {
        // ---- stage phase ----
#pragma unroll
        for (int it = 0; it < 4; ++it) {
            int row = wave * 8 + it * 32 + rowin;
            const u16* ga = A + (size_t)(base + row) * K + kb + achk;
            __builtin_amdgcn_global_load_lds(GLOBAL_AS(ga), LDS_AS(&a_tile[row * 64 + aldst]), 16, 0, 0);
        }
        // pinned half: values already in regs (drained at prior sync_b)
#pragma unroll
        for (int cb = 0; cb < 2; ++cb) {
            int bk8 = bidx_k8 + cb * 2;
            u16 bc[8];
#pragma unroll
            for (int kk = 0; kk < 8; ++kk) bc[kk] = f2bf(bvp[cb][kk]);
            *(short8_t*)&b_tile[bidx_n * 64 + ((bk8 ^ (bidx_n & 7)) * 8)] = *(const short8_t*)bc;
        }
        // transient half: load now (stage waits on 16 loads, not 32)
#pragma unroll
        for (int cb = 0; cb < 2; ++cb) {
            const float* bp = Bm + (size_t)(kb + (bidx_k8 + (cb + 2) * 2) * 8) * N + n0 + bidx_n;
#pragma unroll
            for (int kk = 0; kk < 8; ++kk) bvt[cb][kk] = bp[(size_t)kk * N];
        }
#pragma unroll
        for (int cb = 0; cb < 2; ++cb) {
            int bk8 = bidx_k8 + (cb + 2) * 2;
            u16 bc[8];
#pragma unroll
            for (int kk = 0; kk < 8; ++kk) bc[kk] = f2bf(bvt[cb][kk]);
            *(short8_t*)&b_tile[bidx_n * 64 + ((bk8 ^ (bidx_n & 7)) * 8)] = *(const short8_t*)bc;
        }
        __syncthreads();   // sync_a: tile (kb) visible

        // ---- pinned issue of next pinned-half (covered by MFMA phase) ----
        if (kb + 64 < K) {
#pragma unroll
            for (int cb = 0; cb < 2; ++cb) {
                const float* bp = Bm + (size_t)(kb + 64 + (bidx_k8 + cb * 2) * 8) * N + n0 + bidx_n;
#pragma unroll
                for (int kk = 0; kk < 8; ++kk) {
                    asm volatile("global_load_dword %0, %1, off"
                                 : "=v"(bvp[cb][kk]) : "v"(bp + (size_t)kk * N));
                }
            }
        }

        // ---- compute phase ----
#pragma unroll
        for (int ks = 0; ks < 2; ++ks) {
            const int cp = ((ks * 4 + quad) ^ (r & 7)) * 8;
            short8_t af[4], bfr[4];
#pragma unroll
            for (int i = 0; i < 4; ++i)
                af[i] = *(const short8_t*)&a_tile[(wm + i * 16 + r) * 64 + cp];
#pragma unroll
            for (int j = 0; j < 4; ++j)
                bfr[j] = *(const short8_t*)&b_tile[(wn + j * 16 + r) * 64 + cp];
#pragma unroll
            for (int i = 0; i < 4; ++i)
#pragma unroll
                for (int j = 0; j < 4; ++j)
                    acc[i][j] = __builtin_amdgcn_mfma_f32_16x16x32_bf16(af[i], bfr[j], acc[i][j], 0, 0, 0);
        }
        __syncthreads();   // sync_b: WAR guard + vmcnt(0) drains pinned loads
    }
    // epilogue: bf16 up (halves WRITE traffic; sum still fp32 in combine)
#pragma unroll
    for (int i = 0; i < 4; ++i)
#pragma unroll
        for (int j = 0; j < 4; ++j)
#pragma unroll
            for (int reg = 0; reg < 4; ++reg) {
                int cr = base + wm + i * 16 + quad * 4 + reg;
                int cc = n0 + wn + j * 16 + r;
                up[(size_t)cr * N + cc] = f2bf(acc[i][j][reg]);
            }
}

// ---------------------------------------------------------------------------
// Kernel 5: combine — act[t] = bf16(relu^2(f32(up[p0]) + f32(up[p1])))
// up is bf16 now: read traffic halved (64 -> 32 MB).
// ---------------------------------------------------------------------------
__global__ __launch_bounds__(256) void combine_kernel(
    const u16* __restrict__ up, const int* __restrict__ meta, u16* __restrict__ act) {
    const int t = blockIdx.x;
    const int tid = threadIdx.x;
    const int p0 = meta[M_PAIR + t * 2];
    const int p1 = meta[M_PAIR + t * 2 + 1];
    const u16* r0 = up + (size_t)p0 * 4096;
    const u16* r1 = up + (size_t)p1 * 4096;
    u16* dst = act + (size_t)t * 4096;
#pragma unroll
    for (int it = 0; it < 2; ++it) {
        int i = (tid + it * 256) * 8;
        short8_t a8 = *(const short8_t*)&r0[i];
        short8_t b8 = *(const short8_t*)&r1[i];
        u16 o[8];
#pragma unroll
        for (int j = 0; j < 8; ++j) {
            float s = bf2f((u16)a8[j]) + bf2f((u16)b8[j]);
            s = s > 0.f ? s * s : 0.f;
            o[j] = f2bf(s);
        }
        *(short8_t*)&dst[i] = *(const short8_t*)o;
    }
}

// ---------------------------------------------------------------------------
// Kernel T: transpose + fp32->bf16  in[R][C] fp32 -> out[C][R] bf16
// ---------------------------------------------------------------------------
__global__ __launch_bounds__(256) void transpose_cvt_kernel(
    const float* __restrict__ in, u16* __restrict__ out, int R, int C) {
    __shared__ u16 tile[64][65];
    const int rt = blockIdx.y * 64;
    const int ct = blockIdx.x * 64;
    const int tid = threadIdx.x;
#pragma unroll
    for (int it = 0; it < 2; ++it) {
        int r = (tid >> 3) + it * 32;
        int c8 = (tid & 7) * 8;
        const float* ip = &in[(size_t)(rt + r) * C + ct + c8];
        float4 v0 = *(const float4*)ip;
        float4 v1 = *(const float4*)(ip + 4);
        tile[c8 + 0][r] = f2bf(v0.x); tile[c8 + 1][r] = f2bf(v0.y);
        tile[c8 + 2][r] = f2bf(v0.z); tile[c8 + 3][r] = f2bf(v0.w);
        tile[c8 + 4][r] = f2bf(v1.x); tile[c8 + 5][r] = f2bf(v1.y);
        tile[c8 + 6][r] = f2bf(v1.z); tile[c8 + 7][r] = f2bf(v1.w);
    }
    __syncthreads();
#pragma unroll
    for (int it = 0; it < 2; ++it) {
        int c = (tid >> 3) + it * 32;
        int r8 = (tid & 7) * 8;
        u16 tmp[8];
#pragma unroll
        for (int j = 0; j < 8; ++j) tmp[j] = tile[c][r8 + j];
        *(uint4*)&out[(size_t)(ct + c) * R + rt + r8] = *(const uint4*)tmp;
    }
}

// ---------------------------------------------------------------------------
// Kernel 6: GEMM2 TN split-K — P[z][M][N] = X[M][kchunk] @ Y^T[kchunk]
// R7-exact (verified): all staging via async gload_lds, dbuf 2-phase;
// BM=128 x 4 K-chunks = 512 blocks = 2/CU; m-per-XCD remap.
// ---------------------------------------------------------------------------
template <int BM, int WROWS, int WCOLS>
__global__ __launch_bounds__(256) void gemm_tn_kernel(
    const u16* __restrict__ X, const u16* __restrict__ Y, float* __restrict__ Pout,
    int M, int N, int K) {
    constexpr int WM = BM / WROWS;
    constexpr int WN = 128 / WCOLS;
    constexpr int FI = WM / 16;
    constexpr int FJ = WN / 16;
    __shared__ short a_tile[2][BM * 64];
    __shared__ short b_tile[2][128 * 64];
    const int tid = threadIdx.x;
    const int lane = tid & 63;
    const int wave = tid >> 6;

    const int Nt = gridDim.x, Mt = gridDim.y;
    const int lid = blockIdx.y * Nt + blockIdx.x;
    const int xcd = lid & 7;
    const int p = lid >> 3;
    const int mpx = Mt >> 3;                 // m-tiles per XCD (16/8 = 2)
    const int m_tile = xcd * mpx + (p % mpx);
    const int n_tile = p / mpx;
    const int m0 = m_tile * BM;
    const int n0 = n_tile * 128;
    const int kchunk = K >> 2;               // gridDim.z == 4
    const int kb0 = blockIdx.z * kchunk;

    const int wm = (wave / WCOLS) * WM;
    const int wn = (wave % WCOLS) * WN;
    const int rowin = lane >> 3;
    const int achk = ((lane & 7) ^ (rowin & 7)) * 8;
    const int aldst = (lane & 7) * 8;
    const int r = lane & 15;
    const int quad = lane >> 4;

    const f32x4 vzero = {0.f, 0.f, 0.f, 0.f};
    f32x4 acc[FI][FJ];
#pragma unroll
    for (int i = 0; i < FI; ++i)
#pragma unroll
        for (int j = 0; j < FJ; ++j) acc[i][j] = vzero;

#define G2_STAGE(kb_, buf)                                                            \
    {                                                                                 \
        const int kbc = (kb_);                                                        \
        _Pragma("unroll")                                                             \
        for (int it = 0; it < BM / 32; ++it) {                                        \
            int row = wave * 8 + it * 32 + rowin;                                     \
            const u16* ga = X + (size_t)(m0 + row) * K + kbc + achk;                  \
            __builtin_amdgcn_global_load_lds(GLOBAL_AS(ga),                           \
                LDS_AS(&a_tile[buf][row * 64 + aldst]), 16, 0, 0);                    \
        }                                                                             \
        _Pragma("unroll")                                                             \
        for (int it = 0; it < 4; ++it) {                                              \
            int row = wave * 8 + it * 32 + rowin;                                     \
            const u16* gb = Y + (size_t)(n0 + row) * K + kbc + achk;                  \
            __builtin_amdgcn_global_load_lds(GLOBAL_AS(gb),                           \
                LDS_AS(&b_tile[buf][row * 64 + aldst]), 16, 0, 0);                    \
        }                                                                             \
    }

#define G2_COMPUTE(buf)                                                               \
    {                                                                                 \
        _Pragma("unroll")                                                             \
        for (int ks = 0; ks < 2; ++ks) {                                              \
            const int cp = ((ks * 4 + quad) ^ (r & 7)) * 8;                           \
            short8_t af[FI], bfr[FJ];                                                 \
            _Pragma("unroll")                                                         \
            for (int i = 0; i < FI; ++i)                                              \
                af[i] = *(const short8_t*)&a_tile[buf][(wm + i * 16 + r) * 64 + cp];  \
            _Pragma("unroll")                                                         \
            for (int j = 0; j < FJ; ++j)                                              \
                bfr[j] = *(const short8_t*)&b_tile[buf][(wn + j * 16 + r) * 64 + cp]; \
            _Pragma("unroll")                                                         \
            for (int i = 0; i < FI; ++i)                                              \
                _Pragma("unroll")                                                     \
                for (int j = 0; j < FJ; ++j)                                          \
                    acc[i][j] = __builtin_amdgcn_mfma_f32_16x16x32_bf16(              \
                        af[i], bfr[j], acc[i][j], 0, 0, 0);                           \
        }                                                                             \
    }

    const int nk = kchunk >> 6;
    G2_STAGE(kb0, 0);
    __syncthreads();
    for (int t = 0; t < nk - 1; ++t) {
        const int nxt = (t + 1) & 1;
        G2_STAGE(kb0 + (t + 1) * 64, nxt);
        G2_COMPUTE(t & 1);
        __syncthreads();
    }
    G2_COMPUTE((nk - 1) & 1);

#undef G2_STAGE
#undef G2_COMPUTE

    float* Co = Pout + (size_t)blockIdx.z * M * N;
#pragma unroll
    for (int i = 0; i < FI; ++i)
#pragma unroll
        for (int j = 0; j < FJ; ++j)
#pragma unroll
            for (int reg = 0; reg < 4; ++reg) {
                int cr = m0 + wm + i * 16 + quad * 4 + reg;
                int cc = n0 + wn + j * 16 + r;
                Co[(size_t)cr * N + cc] = acc[i][j][reg];
            }
}

// ---------------------------------------------------------------------------
// Kernel 7: reduce 4 split-K partials -> out
// ---------------------------------------------------------------------------
__global__ __launch_bounds__(256) void reduce4_kernel(
    const float* __restrict__ P, float* __restrict__ out) {
    const size_t S = (size_t)2048 * 1024;
    size_t i = ((size_t)blockIdx.x * 256 + threadIdx.x) * 4;
    float4 a = *(const float4*)&P[i];
    float4 b = *(const float4*)&P[S + i];
    float4 c = *(const float4*)&P[2 * S + i];
    float4 d = *(const float4*)&P[3 * S + i];
    float4 o;
    o.x = (a.x + b.x) + (c.x + d.x);
    o.y = (a.y + b.y) + (c.y + d.y);
    o.z = (a.z + b.z) + (c.z + d.z);
    o.w = (a.w + b.w) + (c.w + d.w);
    *(float4*)&out[i] = o;
}

// ---------------------------------------------------------------------------
// Launch
// ---------------------------------------------------------------------------
extern "C" void kernel_launch(void* const* d_in, const int* in_sizes, int n_in,
                              void* d_out, int out_size, void* d_ws, size_t ws_size,
                              hipStream_t stream) {
    const float* h    = (const float*)d_in[0];   // [2048][1024]
    const float* WG   = (const float*)d_in[1];   // [1024][8]
    const float* Wi   = (const float*)d_in[2];   // [8][1024][4096]
    const float* down = (const float*)d_in[3];   // [4096][1024]
    float* out = (float*)d_out;                  // [2048][1024]

    const int T = 2048, H = 1024, I = 4096;

    // workspace layout (proven available >= 120.06 MiB)
    char* ws = (char*)d_ws;
    float* w_gate = (float*)(ws);                      // 64 KiB
    int*   meta   = (int*)(ws + 65536);                // 64 KiB
    u16*   Arow   = (u16*)(ws + 131072);               // 5120*1024*2 = 10 MiB
    u16*   up     = (u16*)(ws + 131072 + 10485760);    // bf16 now: 5120*4096*2 = 40 MiB (80 MiB slot)
    u16*   act    = (u16*)(ws + 131072 + 10485760 + 83886080);            // 16 MiB
    u16*   downT  = (u16*)(ws + 131072 + 10485760 + 83886080 + 16777216); // 8 MiB
    // split-K partials (4 x 8 MiB = 32 MiB fp32) reuse the up slot: combine
    // has already consumed up before gemm2 runs (stream-ordered).
    float* part   = (float*)(ws + 131072 + 10485760);

    gate_topk_kernel<<<T, 64, 0, stream>>>(h, WG, w_gate);
    scan_kernel<<<1, 1024, 0, stream>>>(w_gate, meta);
    gather_a_kernel<<<5120, 256, 0, stream>>>(h, meta, Arow);

    // grouped GEMM1: up to 40 m-tiles x 32 n-tiles; bf16 out
    gemm1_sparse_kernel<<<dim3(32, 40), 256, 0, stream>>>(Arow, Wi, up, meta);

    // combine pairs + relu^2 -> dense act bf16 [2048][4096]
    combine_kernel<<<T, 256, 0, stream>>>(up, meta, act);

    // down^T bf16, then GEMM2 TN split-K=4 -> partials -> reduce -> out
    transpose_cvt_kernel<<<dim3(H / 64, I / 64), 256, 0, stream>>>(down, downT, I, H);
    gemm_tn_kernel<128, 2, 2><<<dim3(H / 128, T / 128, 4), 256, 0, stream>>>(
        act, downT, part, T, H, I);
    reduce4_kernel<<<(T * H) / 1024, 256, 0, stream>>>(part, out);
}